// Round 1
// baseline (507.153 us; speedup 1.0000x reference)
//
#include <hip/hip_runtime.h>

#define N_NODES 100000
#define N_EDGES 1000000
#define N_REL 3
#define N_GRAPHS 512
#define VOCAB 10000
#define DIM 64

// ---------------------------------------------------------------------------
// Kernel 1: build transformed tables T[m][v][j], m=0 root, m=1..3 relations.
// T[m] = embed_table @ W_m   (VOCAB x 64) @ (64 x 64)
// One wave per (m, v) row; lane j owns output column j.
__global__ void build_tables(const float* __restrict__ embed,
                             const float* __restrict__ W_rel,
                             const float* __restrict__ W_root,
                             float* __restrict__ T) {
    int tid = blockIdx.x * 256 + threadIdx.x;    // 4*VOCAB*64 total
    int j   = tid & 63;
    int row = tid >> 6;          // m*VOCAB + v
    int m   = row / VOCAB;
    int v   = row - m * VOCAB;
    const float* W = (m == 0) ? W_root : (W_rel + (size_t)(m - 1) * DIM * DIM);
    float e   = embed[(size_t)v * DIM + j];   // lane j holds embed[v][j]
    float acc = 0.f;
#pragma unroll
    for (int k = 0; k < DIM; ++k) {
        float ek = __shfl(e, k, 64);          // broadcast embed[v][k]
        acc += ek * W[k * DIM + j];           // coalesced row read of W
    }
    T[tid] = acc;
}

// ---------------------------------------------------------------------------
// Kernel 2: per-(relation,dst) edge counts.
__global__ void count_edges(const int* __restrict__ dst,
                            const int* __restrict__ etype,
                            int* __restrict__ cnt) {
    int e = blockIdx.x * 256 + threadIdx.x;
    if (e < N_EDGES) atomicAdd(&cnt[etype[e] * N_NODES + dst[e]], 1);
}

// ---------------------------------------------------------------------------
// Kernel 3: edge scatter. One wave per edge; lane j handles feature j.
// accum[dst][j] += T[1+r][x[src]][j] / cnt[r][dst]
__global__ void edge_scatter(const int* __restrict__ src,
                             const int* __restrict__ dst,
                             const int* __restrict__ etype,
                             const int* __restrict__ x,
                             const float* __restrict__ T,
                             const int* __restrict__ cnt,
                             float* __restrict__ accum) {
    int tid = blockIdx.x * 256 + threadIdx.x;
    int j = tid & 63;
    int e = tid >> 6;
    if (e >= N_EDGES) return;
    int s = src[e];                  // wave-uniform loads (single request)
    int d = dst[e];
    int r = etype[e];
    int v = x[s];
    float inv = 1.0f / (float)cnt[r * N_NODES + d];   // cnt >= 1 for this edge
    float val = T[((size_t)(1 + r) * VOCAB + v) * DIM + j] * inv;
    atomicAdd(&accum[(size_t)d * DIM + j], val);
}

// ---------------------------------------------------------------------------
// Kernel 4: node pass: root + bias + accum, ReLU, pool scatter.
__global__ void node_pool(const int* __restrict__ x,
                          const int* __restrict__ batch,
                          const float* __restrict__ T,       // T[0] = root table
                          const float* __restrict__ accum,
                          const float* __restrict__ bias,
                          float* __restrict__ g_sum,
                          int* __restrict__ g_cnt) {
    int tid = blockIdx.x * 256 + threadIdx.x;
    int j = tid & 63;
    int i = tid >> 6;
    if (i >= N_NODES) return;
    int v = x[i];
    int g = batch[i];
    float o = T[(size_t)v * DIM + j] + bias[j] + accum[(size_t)i * DIM + j];
    o = fmaxf(o, 0.f);
    atomicAdd(&g_sum[(size_t)g * DIM + j], o);
    if (j == 0) atomicAdd(&g_cnt[g], 1);
}

// ---------------------------------------------------------------------------
// Kernel 5: per-graph mean + 64->2 linear. One 64-lane block per graph.
__global__ void final_linear(const float* __restrict__ g_sum,
                             const int* __restrict__ g_cnt,
                             const float* __restrict__ lin_W,
                             const float* __restrict__ lin_b,
                             float* __restrict__ out) {
    int g = blockIdx.x;
    int j = threadIdx.x;   // 0..63
    float c    = fmaxf((float)g_cnt[g], 1.0f);
    float mean = g_sum[(size_t)g * DIM + j] / c;
    float p0 = mean * lin_W[j * 2 + 0];
    float p1 = mean * lin_W[j * 2 + 1];
#pragma unroll
    for (int off = 32; off > 0; off >>= 1) {
        p0 += __shfl_down(p0, off, 64);
        p1 += __shfl_down(p1, off, 64);
    }
    if (j == 0) {
        out[g * 2 + 0] = p0 + lin_b[0];
        out[g * 2 + 1] = p1 + lin_b[1];
    }
}

// ---------------------------------------------------------------------------
extern "C" void kernel_launch(void* const* d_in, const int* in_sizes, int n_in,
                              void* d_out, int out_size, void* d_ws, size_t ws_size,
                              hipStream_t stream) {
    const int*   x      = (const int*)d_in[0];
    const int*   eidx   = (const int*)d_in[1];   // [2, E]
    const int*   etype  = (const int*)d_in[2];
    const int*   batch  = (const int*)d_in[3];
    const float* embed  = (const float*)d_in[4];
    const float* W_rel  = (const float*)d_in[5];
    const float* W_root = (const float*)d_in[6];
    const float* bias   = (const float*)d_in[7];
    const float* lin_W  = (const float*)d_in[8];
    const float* lin_b  = (const float*)d_in[9];
    float* out = (float*)d_out;

    const int* src = eidx;
    const int* dst = eidx + N_EDGES;

    // Workspace layout (bytes):
    //   accum : N_NODES*64*4        = 25,600,000
    //   cnt   : 3*N_NODES*4         =  1,200,000
    //   T     : 4*VOCAB*64*4        = 10,240,000
    //   g_sum : 512*64*4            =    131,072
    //   g_cnt : 512*4               =      2,048
    char* ws = (char*)d_ws;
    float* accum = (float*)(ws);
    int*   cnt   = (int*)  (ws + 25600000);
    float* T     = (float*)(ws + 26800000);
    float* g_sum = (float*)(ws + 37040000);
    int*   g_cnt = (int*)  (ws + 37171072);

    // Zero accumulators (graph-capture-safe async memsets).
    hipMemsetAsync(ws, 0, 26800000, stream);                 // accum + cnt
    hipMemsetAsync(ws + 37040000, 0, 131072 + 2048, stream); // g_sum + g_cnt

    // 1. transformed tables: 4*VOCAB rows, wave per row
    build_tables<<<(4 * VOCAB * DIM) / 256, 256, 0, stream>>>(embed, W_rel, W_root, T);

    // 2. counts
    count_edges<<<(N_EDGES + 255) / 256, 256, 0, stream>>>(dst, etype, cnt);

    // 3. edge scatter (wave per edge)
    edge_scatter<<<(N_EDGES * 64) / 256, 256, 0, stream>>>(src, dst, etype, x, T, cnt, accum);

    // 4. node pass + pooling scatter (wave per node)
    node_pool<<<(N_NODES * 64 + 255) / 256, 256, 0, stream>>>(x, batch, T, accum, bias, g_sum, g_cnt);

    // 5. per-graph mean + linear
    final_linear<<<N_GRAPHS, 64, 0, stream>>>(g_sum, g_cnt, lin_W, lin_b, out);
}

// Round 2
// 240.064 us; speedup vs baseline: 2.1126x; 2.1126x over previous
//
#include <hip/hip_runtime.h>

#define N_NODES 100000
#define N_EDGES 1000000
#define N_REL 3
#define N_GRAPHS 512
#define VOCAB 10000
#define DIM 64

#define SCAN_B 1024
#define N_SCAN_BLOCKS ((N_NODES + SCAN_B - 1) / SCAN_B)   // 98

// ---------------------------------------------------------------------------
// Kernel 1: build transformed tables T[m][v][j], m=0 root, m=1..3 relations.
// T[m] = embed_table @ W_m   (VOCAB x 64) @ (64 x 64). One wave per row.
__global__ void build_tables(const float* __restrict__ embed,
                             const float* __restrict__ W_rel,
                             const float* __restrict__ W_root,
                             float* __restrict__ T) {
    int tid = blockIdx.x * 256 + threadIdx.x;    // 4*VOCAB*64 total
    int j   = tid & 63;
    int row = tid >> 6;          // m*VOCAB + v
    int m   = row / VOCAB;
    int v   = row - m * VOCAB;
    const float* W = (m == 0) ? W_root : (W_rel + (size_t)(m - 1) * DIM * DIM);
    float e   = embed[(size_t)v * DIM + j];   // lane j holds embed[v][j]
    float acc = 0.f;
#pragma unroll
    for (int k = 0; k < DIM; ++k) {
        float ek = __shfl(e, k, 64);          // broadcast embed[v][k]
        acc += ek * W[k * DIM + j];           // coalesced row read of W
    }
    T[tid] = acc;
}

// ---------------------------------------------------------------------------
// Kernel 2: per-dst degree histogram (int atomics only).
__global__ void hist_deg(const int* __restrict__ dst, int* __restrict__ deg) {
    int e = blockIdx.x * 256 + threadIdx.x;
    if (e < N_EDGES) atomicAdd(&deg[dst[e]], 1);
}

// ---------------------------------------------------------------------------
// Kernel 3a: per-block exclusive scan of deg (1024-wide blocks).
__global__ __launch_bounds__(SCAN_B)
void scan_block(const int* __restrict__ deg, int* __restrict__ off,
                int* __restrict__ bsum) {
    __shared__ int s[SCAN_B];
    int i = blockIdx.x * SCAN_B + threadIdx.x;
    int v = (i < N_NODES) ? deg[i] : 0;
    s[threadIdx.x] = v;
    __syncthreads();
    for (int d = 1; d < SCAN_B; d <<= 1) {
        int t = (threadIdx.x >= d) ? s[threadIdx.x - d] : 0;
        __syncthreads();
        s[threadIdx.x] += t;
        __syncthreads();
    }
    if (i < N_NODES) off[i] = s[threadIdx.x] - v;     // exclusive
    if (threadIdx.x == SCAN_B - 1) bsum[blockIdx.x] = s[SCAN_B - 1];
}

// Kernel 3b: serial exclusive scan of 98 block sums (trivial size).
__global__ void scan_bsum(int* __restrict__ bsum) {
    if (blockIdx.x == 0 && threadIdx.x == 0) {
        int acc = 0;
        for (int b = 0; b < N_SCAN_BLOCKS; ++b) {
            int t = bsum[b]; bsum[b] = acc; acc += t;
        }
    }
}

// Kernel 3c: add block offsets; also init cursor and off[N].
__global__ void scan_add(int* __restrict__ off, const int* __restrict__ bsum,
                         int* __restrict__ cursor) {
    int i = blockIdx.x * 256 + threadIdx.x;
    if (i < N_NODES) {
        int o = off[i] + bsum[i >> 10];
        off[i] = o;
        cursor[i] = o;
    }
    if (i == 0) off[N_NODES] = N_EDGES;
}

// ---------------------------------------------------------------------------
// Kernel 4: scatter packed edge payload (x[src]<<2 | rel) into CSR buckets.
__global__ void scatter_edges(const int* __restrict__ src,
                              const int* __restrict__ dst,
                              const int* __restrict__ etype,
                              const int* __restrict__ x,
                              int* __restrict__ cursor,
                              unsigned short* __restrict__ elist) {
    int e = blockIdx.x * 256 + threadIdx.x;
    if (e >= N_EDGES) return;
    int d = dst[e];
    int pos = atomicAdd(&cursor[d], 1);
    elist[pos] = (unsigned short)(((unsigned)x[src[e]] << 2) | (unsigned)etype[e]);
}

// ---------------------------------------------------------------------------
// Kernel 5: per-dst aggregation. One wave per node; lane j = feature j.
// node_out[d] = relu(T0[x[d]] + bias + sum_r agg_r/max(cnt_r,1))
__global__ void aggregate(const int* __restrict__ x,
                          const int* __restrict__ off,
                          const unsigned short* __restrict__ elist,
                          const float* __restrict__ T,
                          const float* __restrict__ bias,
                          float* __restrict__ node_out) {
    int tid = blockIdx.x * 256 + threadIdx.x;
    int j = tid & 63;
    int w = tid >> 6;                  // dst node id
    if (w >= N_NODES) return;
    int beg = off[w], end = off[w + 1];
    float a0 = 0.f, a1 = 0.f, a2 = 0.f;
    int c0 = 0, c1 = 0, c2 = 0;
    for (int base = beg; base < end; base += 64) {
        int nb = end - base; if (nb > 64) nb = 64;
        // lane-parallel fetch of up to 64 edge payloads, then shfl-broadcast
        int pl = (int)elist[base + (j < nb ? j : 0)];
        for (int k = 0; k < nb; ++k) {
            int p = __shfl(pl, k, 64);       // wave-uniform payload
            int r = p & 3;
            int v = p >> 2;
            float t = T[((size_t)(1 + r) * VOCAB + v) * DIM + j];
            if (r == 0)      { a0 += t; c0++; }
            else if (r == 1) { a1 += t; c1++; }
            else             { a2 += t; c2++; }
        }
    }
    float o = T[(size_t)x[w] * DIM + j] + bias[j]
            + a0 / fmaxf((float)c0, 1.f)
            + a1 / fmaxf((float)c1, 1.f)
            + a2 / fmaxf((float)c2, 1.f);
    node_out[(size_t)w * DIM + j] = fmaxf(o, 0.f);
}

// ---------------------------------------------------------------------------
// Kernel 6: per-graph mean pool + 64->2 linear. batch is SORTED: one block
// per graph binary-searches its node range. 256 threads = 4 waves.
__device__ __forceinline__ int lbound(const int* __restrict__ b, int val) {
    int lo = 0, hi = N_NODES;
    while (lo < hi) {
        int mid = (lo + hi) >> 1;
        if (b[mid] < val) lo = mid + 1; else hi = mid;
    }
    return lo;
}

__global__ void pool_linear(const int* __restrict__ batch,
                            const float* __restrict__ node_out,
                            const float* __restrict__ lin_W,
                            const float* __restrict__ lin_b,
                            float* __restrict__ out) {
    __shared__ float sh[256];
    int g = blockIdx.x;
    int lane = threadIdx.x & 63;
    int w = threadIdx.x >> 6;      // 0..3
    int s = lbound(batch, g);
    int e = lbound(batch, g + 1);
    float acc = 0.f;
    for (int i = s + w; i < e; i += 4)
        acc += node_out[(size_t)i * DIM + lane];
    sh[threadIdx.x] = acc;
    __syncthreads();
    if (w == 0) {
        float tot = sh[lane] + sh[64 + lane] + sh[128 + lane] + sh[192 + lane];
        float cnt = (float)(e - s);
        float mean = (e > s) ? tot / cnt : 0.f;
        float p0 = mean * lin_W[lane * 2 + 0];
        float p1 = mean * lin_W[lane * 2 + 1];
#pragma unroll
        for (int off2 = 32; off2 > 0; off2 >>= 1) {
            p0 += __shfl_down(p0, off2, 64);
            p1 += __shfl_down(p1, off2, 64);
        }
        if (lane == 0) {
            out[g * 2 + 0] = p0 + lin_b[0];
            out[g * 2 + 1] = p1 + lin_b[1];
        }
    }
}

// ---------------------------------------------------------------------------
extern "C" void kernel_launch(void* const* d_in, const int* in_sizes, int n_in,
                              void* d_out, int out_size, void* d_ws, size_t ws_size,
                              hipStream_t stream) {
    const int*   x      = (const int*)d_in[0];
    const int*   eidx   = (const int*)d_in[1];   // [2, E]
    const int*   etype  = (const int*)d_in[2];
    const int*   batch  = (const int*)d_in[3];
    const float* embed  = (const float*)d_in[4];
    const float* W_rel  = (const float*)d_in[5];
    const float* W_root = (const float*)d_in[6];
    const float* bias   = (const float*)d_in[7];
    const float* lin_W  = (const float*)d_in[8];
    const float* lin_b  = (const float*)d_in[9];
    float* out = (float*)d_out;

    const int* src = eidx;
    const int* dst = eidx + N_EDGES;

    // Workspace layout (bytes):
    //   elist    : 1M * 2             = 2,000,000   (first 400,000 aliased as deg:
    //                                                deg is dead before scatter runs)
    //   off      : (N+1)*4            =   400,016 (padded)
    //   cursor   : N*4                =   400,000
    //   bsum     : 512*4              =     2,048
    //   (align 128)
    //   T        : 4*VOCAB*64*4       = 10,240,000
    //   node_out : N*64*4             = 25,600,000
    //   total ≈ 38.65 MB
    char* ws = (char*)d_ws;
    unsigned short* elist = (unsigned short*)(ws);
    int* deg    = (int*)(ws);                    // alias: dead before elist written
    int* off    = (int*)(ws + 2000000);
    int* cursor = (int*)(ws + 2400016);
    int* bsum   = (int*)(ws + 2800016);
    float* T        = (float*)(ws + 2802176);
    float* node_out = (float*)(ws + 13042176);

    // Zero only the degree histogram.
    hipMemsetAsync(deg, 0, N_NODES * sizeof(int), stream);

    // 1. transformed tables
    build_tables<<<(4 * VOCAB * DIM) / 256, 256, 0, stream>>>(embed, W_rel, W_root, T);

    // 2. degree histogram
    hist_deg<<<(N_EDGES + 255) / 256, 256, 0, stream>>>(dst, deg);

    // 3. exclusive scan deg -> off (+cursor copy)
    scan_block<<<N_SCAN_BLOCKS, SCAN_B, 0, stream>>>(deg, off, bsum);
    scan_bsum<<<1, 64, 0, stream>>>(bsum);
    scan_add<<<(N_NODES + 255) / 256, 256, 0, stream>>>(off, bsum, cursor);

    // 4. CSR scatter of packed payloads (overwrites deg alias region — deg is dead)
    scatter_edges<<<(N_EDGES + 255) / 256, 256, 0, stream>>>(src, dst, etype, x, cursor, elist);

    // 5. per-node aggregation (no atomics)
    aggregate<<<(N_NODES * 64) / 256, 256, 0, stream>>>(x, off, elist, T, bias, node_out);

    // 6. per-graph pool + linear (no atomics)
    pool_linear<<<N_GRAPHS, 256, 0, stream>>>(batch, node_out, lin_W, lin_b, out);
}

// Round 3
// 209.584 us; speedup vs baseline: 2.4198x; 1.1454x over previous
//
#include <hip/hip_runtime.h>

#define N_NODES 100000
#define N_EDGES 1000000
#define N_REL 3
#define N_GRAPHS 512
#define VOCAB 10000
#define DIM 64

#define SCAN_B 1024
#define N_SCAN_BLOCKS ((N_NODES + SCAN_B - 1) / SCAN_B)   // 98

// ---------------------------------------------------------------------------
// Kernel 1: build transformed tables T[m][v][j], m=0 root, m=1..3 relations.
// T[m] = embed_table @ W_m   (VOCAB x 64) @ (64 x 64).
// v2: 4 rows per wave. lane = (sub<<4)|q : row sub, feature-quad q.
// Each thread: 256 FMA, 64 bpermutes (1:4 ds:fma), float4 W loads (L1-hot).
__global__ void build_tables(const float* __restrict__ embed,
                             const float* __restrict__ W_rel,
                             const float* __restrict__ W_root,
                             float* __restrict__ T) {
    int tid  = blockIdx.x * 256 + threadIdx.x;
    int l    = tid & 63;
    int wave = tid >> 6;              // 0..9999
    int sub  = l >> 4;                // row-within-wave 0..3
    int q    = l & 15;                // feature quad
    int row  = wave * 4 + sub;        // 0..39999 ; wave never crosses m (10000%4==0)
    int m    = row / VOCAB;
    int v    = row - m * VOCAB;
    const float* W = (m == 0) ? W_root : (W_rel + (size_t)(m - 1) * DIM * DIM);
    // lane holds e[row][4q..4q+3]
    float4 e4  = *(const float4*)(embed + (size_t)v * DIM + q * 4);
    float4 acc = {0.f, 0.f, 0.f, 0.f};
#pragma unroll
    for (int kk = 0; kk < 16; ++kk) {           // k = 4kk .. 4kk+3
        int srcl = sub * 16 + kk;               // lane holding e[row][4kk..4kk+3]
        float ex = __shfl(e4.x, srcl, 64);
        float ey = __shfl(e4.y, srcl, 64);
        float ez = __shfl(e4.z, srcl, 64);
        float ew = __shfl(e4.w, srcl, 64);
        const float4 w0 = *(const float4*)(W + (4 * kk + 0) * DIM + q * 4);
        const float4 w1 = *(const float4*)(W + (4 * kk + 1) * DIM + q * 4);
        const float4 w2 = *(const float4*)(W + (4 * kk + 2) * DIM + q * 4);
        const float4 w3 = *(const float4*)(W + (4 * kk + 3) * DIM + q * 4);
        acc.x += ex * w0.x; acc.y += ex * w0.y; acc.z += ex * w0.z; acc.w += ex * w0.w;
        acc.x += ey * w1.x; acc.y += ey * w1.y; acc.z += ey * w1.z; acc.w += ey * w1.w;
        acc.x += ez * w2.x; acc.y += ez * w2.y; acc.z += ez * w2.z; acc.w += ez * w2.w;
        acc.x += ew * w3.x; acc.y += ew * w3.y; acc.z += ew * w3.z; acc.w += ew * w3.w;
    }
    *(float4*)(T + (size_t)row * DIM + q * 4) = acc;
}

// ---------------------------------------------------------------------------
// Kernel 2: per-dst degree histogram (int atomics only).
__global__ void hist_deg(const int* __restrict__ dst, int* __restrict__ deg) {
    int e = blockIdx.x * 256 + threadIdx.x;
    if (e < N_EDGES) atomicAdd(&deg[dst[e]], 1);
}

// ---------------------------------------------------------------------------
// Kernel 3a: per-block exclusive scan of deg (1024-wide blocks).
__global__ __launch_bounds__(SCAN_B)
void scan_block(const int* __restrict__ deg, int* __restrict__ off,
                int* __restrict__ bsum) {
    __shared__ int s[SCAN_B];
    int i = blockIdx.x * SCAN_B + threadIdx.x;
    int v = (i < N_NODES) ? deg[i] : 0;
    s[threadIdx.x] = v;
    __syncthreads();
    for (int d = 1; d < SCAN_B; d <<= 1) {
        int t = (threadIdx.x >= d) ? s[threadIdx.x - d] : 0;
        __syncthreads();
        s[threadIdx.x] += t;
        __syncthreads();
    }
    if (i < N_NODES) off[i] = s[threadIdx.x] - v;     // exclusive
    if (threadIdx.x == SCAN_B - 1) bsum[blockIdx.x] = s[SCAN_B - 1];
}

// Kernel 3b: serial exclusive scan of 98 block sums (trivial size).
__global__ void scan_bsum(int* __restrict__ bsum) {
    if (blockIdx.x == 0 && threadIdx.x == 0) {
        int acc = 0;
        for (int b = 0; b < N_SCAN_BLOCKS; ++b) {
            int t = bsum[b]; bsum[b] = acc; acc += t;
        }
    }
}

// Kernel 3c: add block offsets; also init cursor and off[N].
__global__ void scan_add(int* __restrict__ off, const int* __restrict__ bsum,
                         int* __restrict__ cursor) {
    int i = blockIdx.x * 256 + threadIdx.x;
    if (i < N_NODES) {
        int o = off[i] + bsum[i >> 10];
        off[i] = o;
        cursor[i] = o;
    }
    if (i == 0) off[N_NODES] = N_EDGES;
}

// ---------------------------------------------------------------------------
// Kernel 4: scatter packed edge payload (x[src]<<2 | rel) into CSR buckets.
__global__ void scatter_edges(const int* __restrict__ src,
                              const int* __restrict__ dst,
                              const int* __restrict__ etype,
                              const int* __restrict__ x,
                              int* __restrict__ cursor,
                              unsigned short* __restrict__ elist) {
    int e = blockIdx.x * 256 + threadIdx.x;
    if (e >= N_EDGES) return;
    int d = dst[e];
    int pos = atomicAdd(&cursor[d], 1);
    elist[pos] = (unsigned short)(((unsigned)x[src[e]] << 2) | (unsigned)etype[e]);
}

// ---------------------------------------------------------------------------
// Kernel 5 v2: per-dst aggregation, 4 edges per wave-iteration.
// lane = (g<<4)|q : g = edge slot 0..3, q = feature quad.
// Pass 1: per-relation counts; pass 2: acc += T_r[v] * inv[r]  (float4).
__global__ void aggregate(const int* __restrict__ x,
                          const int* __restrict__ off,
                          const unsigned short* __restrict__ elist,
                          const float* __restrict__ T,
                          const float* __restrict__ bias,
                          float* __restrict__ node_out) {
    int tid = blockIdx.x * 256 + threadIdx.x;
    int w = tid >> 6;                  // dst node id
    if (w >= N_NODES) return;
    int l = tid & 63;
    int g = l >> 4;                    // edge slot
    int q = l & 15;                    // feature quad
    int beg = off[w], end = off[w + 1];

    // pass 1: per-relation edge counts (group-partial, then combine)
    int c0 = 0, c1 = 0, c2 = 0;
    for (int base = beg + g; base < end; base += 4) {
        int r = (int)elist[base] & 3;
        c0 += (r == 0); c1 += (r == 1); c2 += (r == 2);
    }
    c0 += __shfl_xor(c0, 16, 64); c0 += __shfl_xor(c0, 32, 64);
    c1 += __shfl_xor(c1, 16, 64); c1 += __shfl_xor(c1, 32, 64);
    c2 += __shfl_xor(c2, 16, 64); c2 += __shfl_xor(c2, 32, 64);
    float inv0 = 1.f / fmaxf((float)c0, 1.f);
    float inv1 = 1.f / fmaxf((float)c1, 1.f);
    float inv2 = 1.f / fmaxf((float)c2, 1.f);

    // pass 2: scaled accumulation (elist re-read is L1-hot)
    float4 acc = {0.f, 0.f, 0.f, 0.f};
    for (int base = beg + g; base < end; base += 4) {
        unsigned p = elist[base];
        int r = (int)(p & 3u);
        int v = (int)(p >> 2);
        const float4 t = *(const float4*)(T + ((size_t)(1 + r) * VOCAB + v) * DIM + q * 4);
        float inv = (r == 0) ? inv0 : ((r == 1) ? inv1 : inv2);
        acc.x += t.x * inv; acc.y += t.y * inv;
        acc.z += t.z * inv; acc.w += t.w * inv;
    }
    // combine the 4 edge-slot groups
    acc.x += __shfl_xor(acc.x, 16, 64); acc.x += __shfl_xor(acc.x, 32, 64);
    acc.y += __shfl_xor(acc.y, 16, 64); acc.y += __shfl_xor(acc.y, 32, 64);
    acc.z += __shfl_xor(acc.z, 16, 64); acc.z += __shfl_xor(acc.z, 32, 64);
    acc.w += __shfl_xor(acc.w, 16, 64); acc.w += __shfl_xor(acc.w, 32, 64);

    if (g == 0) {                      // lanes 0..15 write the 64-float row
        int v0 = x[w];
        const float4 rt = *(const float4*)(T + (size_t)v0 * DIM + q * 4);
        const float4 b4 = *(const float4*)(bias + q * 4);
        float4 o;
        o.x = fmaxf(rt.x + b4.x + acc.x, 0.f);
        o.y = fmaxf(rt.y + b4.y + acc.y, 0.f);
        o.z = fmaxf(rt.z + b4.z + acc.z, 0.f);
        o.w = fmaxf(rt.w + b4.w + acc.w, 0.f);
        *(float4*)(node_out + (size_t)w * DIM + q * 4) = o;
    }
}

// ---------------------------------------------------------------------------
// Kernel 6: per-graph mean pool + 64->2 linear. batch is SORTED: one block
// per graph binary-searches its node range. 256 threads = 4 waves.
__device__ __forceinline__ int lbound(const int* __restrict__ b, int val) {
    int lo = 0, hi = N_NODES;
    while (lo < hi) {
        int mid = (lo + hi) >> 1;
        if (b[mid] < val) lo = mid + 1; else hi = mid;
    }
    return lo;
}

__global__ void pool_linear(const int* __restrict__ batch,
                            const float* __restrict__ node_out,
                            const float* __restrict__ lin_W,
                            const float* __restrict__ lin_b,
                            float* __restrict__ out) {
    __shared__ float sh[256];
    int g = blockIdx.x;
    int lane = threadIdx.x & 63;
    int w = threadIdx.x >> 6;      // 0..3
    int s = lbound(batch, g);
    int e = lbound(batch, g + 1);
    float acc = 0.f;
    for (int i = s + w; i < e; i += 4)
        acc += node_out[(size_t)i * DIM + lane];
    sh[threadIdx.x] = acc;
    __syncthreads();
    if (w == 0) {
        float tot = sh[lane] + sh[64 + lane] + sh[128 + lane] + sh[192 + lane];
        float cnt = (float)(e - s);
        float mean = (e > s) ? tot / cnt : 0.f;
        float p0 = mean * lin_W[lane * 2 + 0];
        float p1 = mean * lin_W[lane * 2 + 1];
#pragma unroll
        for (int off2 = 32; off2 > 0; off2 >>= 1) {
            p0 += __shfl_down(p0, off2, 64);
            p1 += __shfl_down(p1, off2, 64);
        }
        if (lane == 0) {
            out[g * 2 + 0] = p0 + lin_b[0];
            out[g * 2 + 1] = p1 + lin_b[1];
        }
    }
}

// ---------------------------------------------------------------------------
extern "C" void kernel_launch(void* const* d_in, const int* in_sizes, int n_in,
                              void* d_out, int out_size, void* d_ws, size_t ws_size,
                              hipStream_t stream) {
    const int*   x      = (const int*)d_in[0];
    const int*   eidx   = (const int*)d_in[1];   // [2, E]
    const int*   etype  = (const int*)d_in[2];
    const int*   batch  = (const int*)d_in[3];
    const float* embed  = (const float*)d_in[4];
    const float* W_rel  = (const float*)d_in[5];
    const float* W_root = (const float*)d_in[6];
    const float* bias   = (const float*)d_in[7];
    const float* lin_W  = (const float*)d_in[8];
    const float* lin_b  = (const float*)d_in[9];
    float* out = (float*)d_out;

    const int* src = eidx;
    const int* dst = eidx + N_EDGES;

    // Workspace layout (bytes):
    //   elist    : 1M * 2             = 2,000,000  (first 400,000 aliased as deg:
    //                                               deg is dead before scatter runs)
    //   off      : (N+1)*4            =   400,016 (padded)
    //   cursor   : N*4                =   400,000
    //   bsum     : 512*4              =     2,048
    //   T        : 4*VOCAB*64*4       = 10,240,000
    //   node_out : N*64*4             = 25,600,000
    char* ws = (char*)d_ws;
    unsigned short* elist = (unsigned short*)(ws);
    int* deg    = (int*)(ws);                    // alias: dead before elist written
    int* off    = (int*)(ws + 2000000);
    int* cursor = (int*)(ws + 2400016);
    int* bsum   = (int*)(ws + 2800016);
    float* T        = (float*)(ws + 2802176);
    float* node_out = (float*)(ws + 13042176);

    // Zero only the degree histogram.
    hipMemsetAsync(deg, 0, N_NODES * sizeof(int), stream);

    // 1. transformed tables (independent of CSR chain)
    build_tables<<<(4 * VOCAB) / 16, 256, 0, stream>>>(embed, W_rel, W_root, T);

    // 2. degree histogram
    hist_deg<<<(N_EDGES + 255) / 256, 256, 0, stream>>>(dst, deg);

    // 3. exclusive scan deg -> off (+cursor copy)
    scan_block<<<N_SCAN_BLOCKS, SCAN_B, 0, stream>>>(deg, off, bsum);
    scan_bsum<<<1, 64, 0, stream>>>(bsum);
    scan_add<<<(N_NODES + 255) / 256, 256, 0, stream>>>(off, bsum, cursor);

    // 4. CSR scatter of packed payloads (overwrites deg alias region — deg is dead)
    scatter_edges<<<(N_EDGES + 255) / 256, 256, 0, stream>>>(src, dst, etype, x, cursor, elist);

    // 5. per-node aggregation (no atomics, 4 edges / wave-iteration)
    aggregate<<<(N_NODES * 64) / 256, 256, 0, stream>>>(x, off, elist, T, bias, node_out);

    // 6. per-graph pool + linear (no atomics)
    pool_linear<<<N_GRAPHS, 256, 0, stream>>>(batch, node_out, lin_W, lin_b, out);
}